// Round 11
// baseline (450.864 us; speedup 1.0000x reference)
//
#include <hip/hip_runtime.h>
#include <math.h>

#define Bb 4
#define Tt 2048
#define Cc 1024
#define Hh 16
#define Dd 64
#define FFf 2048
#define Mrows (Bb*Tt)   // 8192

typedef _Float16 f16;
typedef _Float16 half8 __attribute__((ext_vector_type(8)));
typedef _Float16 half4 __attribute__((ext_vector_type(4)));
typedef _Float16 half2 __attribute__((ext_vector_type(2)));
typedef float floatx4 __attribute__((ext_vector_type(4)));
typedef float floatx16 __attribute__((ext_vector_type(16)));

#define MFMA16(a,b,c)    __builtin_amdgcn_mfma_f32_16x16x32_f16(a,b,c,0,0,0)
#define MFMA16K16(a,b,c) __builtin_amdgcn_mfma_f32_16x16x16f16(a,b,c,0,0,0)
#define MFMA32(a,b,c)    __builtin_amdgcn_mfma_f32_32x32x16_f16(a,b,c,0,0,0)

// async global->LDS, 16B per lane; LDS dest = wave-uniform base + lane*16
__device__ __forceinline__ void g2l16(const void* g, void* l) {
  __builtin_amdgcn_global_load_lds((__attribute__((address_space(1))) void*)(g),
                                   (__attribute__((address_space(3))) void*)(l),
                                   16, 0, 0);
}

// ------- merged weight convert+transpose: W[K][N] f32 -> WT[N][K] f16 (all 4 weights) -------
__global__ __launch_bounds__(256) void wt_all_kernel(
    const float* __restrict__ Wqkv, const float* __restrict__ Wproj,
    const float* __restrict__ Wff1, const float* __restrict__ Wff2,
    f16* __restrict__ WqkvT, f16* __restrict__ WprojT,
    f16* __restrict__ Wff1T, f16* __restrict__ Wff2T) {
  __shared__ float tile[32][33];
  int idx = blockIdx.x;
  const float* W; f16* WT; int K, N, n0, k0;
  if (idx < 3072)      { W = Wqkv;  WT = WqkvT;  K = Cc;  N = 3*Cc; n0 = (idx % 96)*32; k0 = (idx / 96)*32; }
  else if (idx < 4096) { idx -= 3072; W = Wproj; WT = WprojT; K = Cc;  N = Cc;  n0 = (idx % 32)*32; k0 = (idx / 32)*32; }
  else if (idx < 6144) { idx -= 4096; W = Wff1;  WT = Wff1T;  K = Cc;  N = FFf; n0 = (idx % 64)*32; k0 = (idx / 64)*32; }
  else                 { idx -= 6144; W = Wff2;  WT = Wff2T;  K = FFf; N = Cc;  n0 = (idx % 32)*32; k0 = (idx / 32)*32; }
  const int tx = threadIdx.x, ty = threadIdx.y;   // block (32,8)
  #pragma unroll
  for (int i = 0; i < 4; i++)
    tile[ty + 8*i][tx] = W[(size_t)(k0 + ty + 8*i) * N + n0 + tx];
  __syncthreads();
  #pragma unroll
  for (int i = 0; i < 4; i++)
    WT[(size_t)(n0 + ty + 8*i) * K + k0 + tx] = (f16)tile[tx][ty + 8*i];
}

// ---------------- LayerNorm: fp32 in -> f16 out ----------------
__global__ __launch_bounds__(256) void ln_kernel(const float* __restrict__ x,
                                                 const float* __restrict__ gam,
                                                 const float* __restrict__ bet,
                                                 f16* __restrict__ out) {
  const int row = blockIdx.x;
  const int tid = threadIdx.x;
  const float4 v = ((const float4*)(x + (size_t)row * Cc))[tid];
  float s  = v.x + v.y + v.z + v.w;
  float ss = v.x*v.x + v.y*v.y + v.z*v.z + v.w*v.w;
  #pragma unroll
  for (int o = 32; o >= 1; o >>= 1) { s += __shfl_xor(s, o); ss += __shfl_xor(ss, o); }
  __shared__ float ps[4], pss[4];
  if ((tid & 63) == 0) { ps[tid >> 6] = s; pss[tid >> 6] = ss; }
  __syncthreads();
  s  = ps[0] + ps[1] + ps[2] + ps[3];
  ss = pss[0] + pss[1] + pss[2] + pss[3];
  const float mu   = s * (1.0f / Cc);
  const float rstd = rsqrtf(ss * (1.0f / Cc) - mu * mu + 1e-5f);
  const float4 g4 = ((const float4*)gam)[tid];
  const float4 b4 = ((const float4*)bet)[tid];
  half4 o;
  o[0] = (f16)((v.x - mu) * rstd * g4.x + b4.x);
  o[1] = (f16)((v.y - mu) * rstd * g4.y + b4.y);
  o[2] = (f16)((v.z - mu) * rstd * g4.z + b4.z);
  o[3] = (f16)((v.w - mu) * rstd * g4.w + b4.w);
  ((half4*)(out + (size_t)row * Cc))[tid] = o;
}

// -------- shared epilogue helper (32x32 C layout: col=lane&31, row=(reg&3)+8*(reg>>2)+4*khalf) --------
template <int MODE>
__device__ __forceinline__ void gemm_epilogue_tile(
    const floatx16& a, int rowBase, int col, int khalf,
    const float* __restrict__ resid, const float* __restrict__ bias,
    float* __restrict__ outF, f16* __restrict__ outH,
    f16* __restrict__ outQ, f16* __restrict__ outK, f16* __restrict__ outV) {
  if (MODE == 0) {
    const int s = col >> 10;
    const int hh = (col >> 6) & 15;
    const int d = col & 63;
    #pragma unroll
    for (int g = 0; g < 4; g++) {
      const int row0 = rowBase + 4*khalf + 8*g;
      const int bI = row0 >> 11;
      const int t0 = row0 & 2047;
      if (s == 2) {
        const size_t addr = (((size_t)(bI*Hh + hh)) * Dd + d) * Tt +
                            (t0 & ~63) + ((t0 >> 2) & 3)*16 + ((t0 >> 4) & 3)*4;
        half4 o;
        #pragma unroll
        for (int r = 0; r < 4; r++) o[r] = (f16)a[g*4 + r];
        *(half4*)&outV[addr] = o;
      } else {
        f16* dst = (s == 0) ? outQ : outK;
        const float sc = (s == 0) ? 0.18033688f : 1.0f;  // (1/8)*log2(e) folded into q
        #pragma unroll
        for (int r = 0; r < 4; r++)
          dst[(((size_t)(bI*Hh + hh)) * Tt + t0 + r) * Dd + d] = (f16)(a[g*4 + r] * sc);
      }
    }
  } else {
    #pragma unroll
    for (int g = 0; g < 4; g++) {
      #pragma unroll
      for (int r = 0; r < 4; r++) {
        const int row = rowBase + 4*khalf + 8*g + r;
        const float vv = a[g*4 + r];
        if (MODE == 1) {
          const size_t ad = (size_t)row * Cc + col;
          outF[ad] = vv + resid[ad] + bias[col];
        } else if (MODE == 2) {
          const float t = vv + bias[col];
          const float gl = 0.5f * t * (1.0f + erff(t * 0.70710678118654752f));
          outH[(size_t)row * FFf + col] = (f16)gl;
        } else {
          const size_t ad = (size_t)row * Cc + col;
          outF[ad] = vv + bias[col] + resid[ad];
        }
      }
    }
  }
}

// ------------- GEMM 128x128: 32x32x16 MFMA, BK=64, swizzled staging (proj/FF2) -------------
template <int MODE>
__global__ __launch_bounds__(256, 3) void gemm_kernel(
    const f16* __restrict__ A, const f16* __restrict__ Bt, const int Kdim,
    const float* __restrict__ resid, const float* __restrict__ bias,
    float* __restrict__ outF, f16* __restrict__ outH,
    f16* __restrict__ outQ, f16* __restrict__ outK, f16* __restrict__ outV) {
  __shared__ f16 As[128 * 64];
  __shared__ f16 Bs[128 * 64];
  const int tid = threadIdx.x;
  const int lane = tid & 63;
  const int w = tid >> 6;
  const int wr = w >> 1, wc = w & 1;
  const int bm = blockIdx.y, bn = blockIdx.x;

  floatx16 acc[2][2] = {};

  const int srow = lane >> 3;
  const int scol = ((lane & 7) ^ srow) * 8;
  const size_t aBase = (size_t)(bm*128 + w*32 + srow) * Kdim + scol;
  const size_t bBase = (size_t)(bn*128 + w*32 + srow) * Kdim + scol;

  const int m0 = wr*64 + (lane & 31);
  const int n0 = wc*64 + (lane & 31);
  const int khalf = lane >> 5;
  const int mx = (lane & 7);

  for (int ks = 0; ks < Kdim; ks += 64) {
    __syncthreads();
    #pragma unroll
    for (int c = 0; c < 4; c++) {
      g2l16(A  + aBase + (size_t)(c*8)*Kdim + ks, &As[(w*32 + c*8) * 64]);
      g2l16(Bt + bBase + (size_t)(c*8)*Kdim + ks, &Bs[(w*32 + c*8) * 64]);
    }
    __syncthreads();
    #pragma unroll
    for (int kk = 0; kk < 4; kk++) {
      const int kg = kk*2 + khalf;
      half8 aF[2], bF[2];
      aF[0] = *(const half8*)&As[(m0     ) * 64 + ((kg ^ mx) * 8)];
      aF[1] = *(const half8*)&As[(m0 + 32) * 64 + ((kg ^ mx) * 8)];
      bF[0] = *(const half8*)&Bs[(n0     ) * 64 + ((kg ^ mx) * 8)];
      bF[1] = *(const half8*)&Bs[(n0 + 32) * 64 + ((kg ^ mx) * 8)];
      acc[0][0] = MFMA32(aF[0], bF[0], acc[0][0]);
      acc[0][1] = MFMA32(aF[0], bF[1], acc[0][1]);
      acc[1][0] = MFMA32(aF[1], bF[0], acc[1][0]);
      acc[1][1] = MFMA32(aF[1], bF[1], acc[1][1]);
    }
  }

  #pragma unroll
  for (int mi = 0; mi < 2; mi++)
    #pragma unroll
    for (int ni = 0; ni < 2; ni++)
      gemm_epilogue_tile<MODE>(acc[mi][ni], blockIdx.y*128 + wr*64 + mi*32,
                               blockIdx.x*128 + wc*64 + ni*32 + (lane & 31), khalf,
                               resid, bias, outF, outH, outQ, outK, outV);
}

// ------------- GEMM 256x128: 512 threads, 8 waves, wave-tile 64x64 (QKV/FF1) -------------
// Stages A once per K-step for 2x the M — 24 KB staged per 128x128-chunk vs 32 KB.
template <int MODE>
__global__ __launch_bounds__(512, 2) void gemm256_kernel(
    const f16* __restrict__ A, const f16* __restrict__ Bt, const int Kdim,
    const float* __restrict__ bias,
    float* __restrict__ outF, f16* __restrict__ outH,
    f16* __restrict__ outQ, f16* __restrict__ outK, f16* __restrict__ outV) {
  __shared__ f16 As[256 * 64];   // 32 KB
  __shared__ f16 Bs[128 * 64];   // 16 KB
  const int tid = threadIdx.x;
  const int lane = tid & 63;
  const int w = tid >> 6;        // 0..7
  const int wr = w >> 1;         // 0..3 row-group (64 rows)
  const int wc = w & 1;          // 0..1 col-group (64 cols)
  const int bm = blockIdx.y, bn = blockIdx.x;

  floatx16 acc[2][2] = {};

  const int srow = tid >> 3;                      // 0..63
  const int scol = ((tid & 7) ^ (srow & 7)) * 8;  // swizzled k-group
  const size_t aBase = (size_t)(bm*256 + srow) * Kdim + scol;
  const size_t bBase = (size_t)(bn*128 + srow) * Kdim + scol;

  const int m0 = wr*64 + (lane & 31);
  const int n0 = wc*64 + (lane & 31);
  const int khalf = lane >> 5;
  const int mx = (lane & 7);

  for (int ks = 0; ks < Kdim; ks += 64) {
    __syncthreads();
    #pragma unroll
    for (int c = 0; c < 4; c++)
      g2l16(A + aBase + (size_t)(c*64)*Kdim + ks, &As[(srow + c*64) * 64]);
    #pragma unroll
    for (int c = 0; c < 2; c++)
      g2l16(Bt + bBase + (size_t)(c*64)*Kdim + ks, &Bs[(srow + c*64) * 64]);
    __syncthreads();
    #pragma unroll
    for (int kk = 0; kk < 4; kk++) {
      const int kg = kk*2 + khalf;
      half8 aF[2], bF[2];
      aF[0] = *(const half8*)&As[(wr*64 + (lane & 31)     ) * 64 + ((kg ^ mx) * 8)];
      aF[1] = *(const half8*)&As[(wr*64 + (lane & 31) + 32) * 64 + ((kg ^ mx) * 8)];
      bF[0] = *(const half8*)&Bs[(n0     ) * 64 + ((kg ^ mx) * 8)];
      bF[1] = *(const half8*)&Bs[(n0 + 32) * 64 + ((kg ^ mx) * 8)];
      acc[0][0] = MFMA32(aF[0], bF[0], acc[0][0]);
      acc[0][1] = MFMA32(aF[0], bF[1], acc[0][1]);
      acc[1][0] = MFMA32(aF[1], bF[0], acc[1][0]);
      acc[1][1] = MFMA32(aF[1], bF[1], acc[1][1]);
    }
  }

  #pragma unroll
  for (int mi = 0; mi < 2; mi++)
    #pragma unroll
    for (int ni = 0; ni < 2; ni++)
      gemm_epilogue_tile<MODE>(acc[mi][ni], bm*256 + wr*64 + mi*32,
                               bn*128 + wc*64 + ni*32 + (lane & 31), khalf,
                               nullptr, bias, outF, outH, outQ, outK, outV);
}

// ---------------- flash attention: 128-q tile, 64-key staging, P in registers ----------------
__global__ __launch_bounds__(256, 4) void attn_kernel(
    const f16* __restrict__ Q, const f16* __restrict__ Kg,
    const f16* __restrict__ Vtp, const int* __restrict__ perm,
    f16* __restrict__ Y) {
  __shared__ f16 Ks[64 * 64];
  __shared__ f16 Vs[64 * 64];
  __shared__ int permS[64];

  const int tid = threadIdx.x;
  const int lane = tid & 63;
  const int w = tid >> 6;
  const int low = lane & 15;
  const int quad = lane >> 4;
  const int bh = blockIdx.y;
  const int q0 = blockIdx.x * 128;
  const int b = bh >> 4, h = bh & 15;

  half8 qF[2][2];
  {
    const size_t base = ((size_t)bh * Tt + q0 + w*32) * Dd;
    #pragma unroll
    for (int qi = 0; qi < 2; qi++)
      #pragma unroll
      for (int kc = 0; kc < 2; kc++)
        qF[qi][kc] = *(const half8*)(Q + base + (size_t)(qi*16 + low) * Dd +
                                     kc*32 + quad*8);
  }

  floatx4 O[4][2] = {};
  floatx4 Ol[2] = {};
  const half4 ones4 = {(f16)1.f, (f16)1.f, (f16)1.f, (f16)1.f};

  const int gd = ((lane & 7) ^ (lane >> 3)) * 8;
  const int krow = lane >> 3;

  for (int kt = 0; kt < Tt / 64; kt++) {
    const int kbase = kt * 64;
    __syncthreads();
    {
      const size_t kgBase = ((size_t)bh * Tt + kbase) * Dd;
      const size_t vgBase = ((size_t)bh * Dd) * Tt + kbase;
      g2l16(Kg  + kgBase + (size_t)(w*16 + 0 + krow) * Dd + gd, &Ks[(w*2 + 0) * 512]);
      g2l16(Kg  + kgBase + (size_t)(w*16 + 8 + krow) * Dd + gd, &Ks[(w*2 + 1) * 512]);
      g2l16(Vtp + vgBase + (size_t)(w*16 + 0 + krow) * Tt + gd, &Vs[(w*2 + 0) * 512]);
      g2l16(Vtp + vgBase + (size_t)(w*16 + 8 + krow) * Tt + gd, &Vs[(w*2 + 1) * 512]);
      if (tid < 64) permS[tid] = perm[kbase + tid];
    }
    __syncthreads();

    floatx4 S[2][4] = {};
    #pragma unroll
    for (int kc = 0; kc < 2; kc++) {
      #pragma unroll
      for (int ki = 0; ki < 4; ki++) {
        const int key = ki*16 + low;
        const half8 kf = *(const half8*)&Ks[key * 64 + (((kc*4 + quad) ^ (lane & 7)) * 8)];
        S[0][ki] = MFMA16(kf, qF[0][kc], S[0][ki]);
        S[1][ki] = MFMA16(kf, qF[1][kc], S[1][ki]);
      }
    }

    int4 pk[4];
    #pragma unroll
    for (int ki = 0; ki < 4; ki++) pk[ki] = *(const int4*)&permS[ki*16 + quad*4];

    half4 pF[2][4];
    #pragma unroll
    for (int qi = 0; qi < 2; qi++) {
      const int qrow = q0 + w*32 + qi*16 + low;
      #pragma unroll
      for (int ki = 0; ki < 4; ki++) {
        const floatx4 sv = S[qi][ki];
        const float p0 = (pk[ki].x > qrow) ? 0.f : __builtin_amdgcn_exp2f(sv[0]);
        const float p1 = (pk[ki].y > qrow) ? 0.f : __builtin_amdgcn_exp2f(sv[1]);
        const float p2 = (pk[ki].z > qrow) ? 0.f : __builtin_amdgcn_exp2f(sv[2]);
        const float p3 = (pk[ki].w > qrow) ? 0.f : __builtin_amdgcn_exp2f(sv[3]);
        const half2 lo = __builtin_bit_cast(half2, __builtin_amdgcn_cvt_pkrtz(p0, p1));
        const half2 hi = __builtin_bit_cast(half2, __builtin_amdgcn_cvt_pkrtz(p2, p3));
        pF[qi][ki] = __builtin_shufflevector(lo, hi, 0, 1, 2, 3);
      }
    }

    #pragma unroll
    for (int ki2 = 0; ki2 < 2; ki2++) {
      Ol[0] = MFMA16K16(ones4, pF[0][2*ki2 + 0], Ol[0]);
      Ol[1] = MFMA16K16(ones4, pF[1][2*ki2 + 0], Ol[1]);
      Ol[0] = MFMA16K16(ones4, pF[0][2*ki2 + 1], Ol[0]);
      Ol[1] = MFMA16K16(ones4, pF[1][2*ki2 + 1], Ol[1]);
      #pragma unroll
      for (int ni = 0; ni < 4; ni++) {
        const int d = ni*16 + low;
        const half8 v8 = *(const half8*)&Vs[d * 64 + (((quad*2 + ki2) ^ (lane & 7)) * 8)];
        const half4 vfA = __builtin_shufflevector(v8, v8, 0, 1, 2, 3);
        const half4 vfB = __builtin_shufflevector(v8, v8, 4, 5, 6, 7);
        O[ni][0] = MFMA16K16(vfA, pF[0][2*ki2 + 0], O[ni][0]);
        O[ni][1] = MFMA16K16(vfA, pF[1][2*ki2 + 0], O[ni][1]);
        O[ni][0] = MFMA16K16(vfB, pF[0][2*ki2 + 1], O[ni][0]);
        O[ni][1] = MFMA16K16(vfB, pF[1][2*ki2 + 1], O[ni][1]);
      }
    }
  }

  #pragma unroll
  for (int qi = 0; qi < 2; qi++) {
    const float linv = 1.0f / Ol[qi][0];
    const int trow = q0 + w*32 + qi*16 + low;
    #pragma unroll
    for (int ni = 0; ni < 4; ni++) {
      half4 o;
      #pragma unroll
      for (int r = 0; r < 4; r++) o[r] = (f16)(O[ni][qi][r] * linv);
      *(half4*)&Y[((size_t)(b * Tt + trow)) * Cc + h*64 + ni*16 + quad*4] = o;
    }
  }
}

extern "C" void kernel_launch(void* const* d_in, const int* in_sizes, int n_in,
                              void* d_out, int out_size, void* d_ws, size_t ws_size,
                              hipStream_t stream) {
  const float* x     = (const float*)d_in[0];
  const int*   perm  = (const int*)d_in[1];
  const float* Wqkv  = (const float*)d_in[2];
  const float* Wproj = (const float*)d_in[3];
  const float* bproj = (const float*)d_in[4];
  const float* ln1g  = (const float*)d_in[5];
  const float* ln1b  = (const float*)d_in[6];
  const float* ln2g  = (const float*)d_in[7];
  const float* ln2b  = (const float*)d_in[8];
  const float* Wff1  = (const float*)d_in[9];
  const float* bff1  = (const float*)d_in[10];
  const float* Wff2  = (const float*)d_in[11];
  const float* bff2  = (const float*)d_in[12];
  float* out = (float*)d_out;

  char* ws = (char*)d_ws;
  size_t off = 0;
  auto alloc = [&](size_t bytes) -> void* {
    void* p = ws + off;
    off += (bytes + 255) & ~(size_t)255;
    return p;
  };
  f16*   h1     = (f16*)alloc((size_t)Mrows * Cc * 2);
  f16*   qb     = (f16*)alloc((size_t)Mrows * Cc * 2);
  f16*   kb     = (f16*)alloc((size_t)Mrows * Cc * 2);
  f16*   vtp    = (f16*)alloc((size_t)Mrows * Cc * 2);
  f16*   yb     = (f16*)alloc((size_t)Mrows * Cc * 2);
  float* xa     = (float*)alloc((size_t)Mrows * Cc * 4);
  f16*   h2     = (f16*)alloc((size_t)Mrows * Cc * 2);
  f16*   gb     = (f16*)alloc((size_t)Mrows * FFf * 2);
  f16*   WqkvT  = (f16*)alloc((size_t)3 * Cc * Cc * 2);
  f16*   WprojT = (f16*)alloc((size_t)Cc * Cc * 2);
  f16*   Wff1T  = (f16*)alloc((size_t)FFf * Cc * 2);
  f16*   Wff2T  = (f16*)alloc((size_t)Cc * FFf * 2);

  wt_all_kernel<<<8192, dim3(32, 8), 0, stream>>>(Wqkv, Wproj, Wff1, Wff2,
                                                  WqkvT, WprojT, Wff1T, Wff2T);

  ln_kernel<<<Mrows, 256, 0, stream>>>(x, ln1g, ln1b, h1);

  gemm256_kernel<0><<<dim3(3*Cc/128, Mrows/256), 512, 0, stream>>>(
      h1, WqkvT, Cc, nullptr, nullptr, nullptr, qb, kb, vtp);

  attn_kernel<<<dim3(Tt/128, Bb*Hh), 256, 0, stream>>>(qb, kb, vtp, perm, yb);

  gemm_kernel<1><<<dim3(Cc/128, Mrows/128), 256, 0, stream>>>(
      yb, WprojT, Cc, x, bproj, xa, nullptr, nullptr, nullptr, nullptr);

  ln_kernel<<<Mrows, 256, 0, stream>>>(xa, ln2g, ln2b, h2);

  gemm256_kernel<2><<<dim3(FFf/128, Mrows/256), 512, 0, stream>>>(
      h2, Wff1T, Cc, bff1, nullptr, gb, nullptr, nullptr, nullptr);

  gemm_kernel<3><<<dim3(Cc/128, Mrows/128), 256, 0, stream>>>(
      gb, Wff2T, FFf, xa, bff2, out, nullptr, nullptr, nullptr, nullptr);
}

// Round 12
// 448.408 us; speedup vs baseline: 1.0055x; 1.0055x over previous
//
#include <hip/hip_runtime.h>
#include <math.h>

#define Bb 4
#define Tt 2048
#define Cc 1024
#define Hh 16
#define Dd 64
#define FFf 2048
#define Mrows (Bb*Tt)   // 8192

typedef _Float16 f16;
typedef _Float16 half8 __attribute__((ext_vector_type(8)));
typedef _Float16 half4 __attribute__((ext_vector_type(4)));
typedef _Float16 half2 __attribute__((ext_vector_type(2)));
typedef float floatx4 __attribute__((ext_vector_type(4)));
typedef float floatx16 __attribute__((ext_vector_type(16)));

#define MFMA16(a,b,c)    __builtin_amdgcn_mfma_f32_16x16x32_f16(a,b,c,0,0,0)
#define MFMA16K16(a,b,c) __builtin_amdgcn_mfma_f32_16x16x16f16(a,b,c,0,0,0)
#define MFMA32(a,b,c)    __builtin_amdgcn_mfma_f32_32x32x16_f16(a,b,c,0,0,0)

// async global->LDS, 16B per lane; LDS dest = wave-uniform base + lane*16
__device__ __forceinline__ void g2l16(const void* g, void* l) {
  __builtin_amdgcn_global_load_lds((__attribute__((address_space(1))) void*)(g),
                                   (__attribute__((address_space(3))) void*)(l),
                                   16, 0, 0);
}

// ------- merged weight convert+transpose: W[K][N] f32 -> WT[N][K] f16 (all 4 weights) -------
__global__ __launch_bounds__(256) void wt_all_kernel(
    const float* __restrict__ Wqkv, const float* __restrict__ Wproj,
    const float* __restrict__ Wff1, const float* __restrict__ Wff2,
    f16* __restrict__ WqkvT, f16* __restrict__ WprojT,
    f16* __restrict__ Wff1T, f16* __restrict__ Wff2T) {
  __shared__ float tile[32][33];
  int idx = blockIdx.x;
  const float* W; f16* WT; int K, N, n0, k0;
  if (idx < 3072)      { W = Wqkv;  WT = WqkvT;  K = Cc;  N = 3*Cc; n0 = (idx % 96)*32; k0 = (idx / 96)*32; }
  else if (idx < 4096) { idx -= 3072; W = Wproj; WT = WprojT; K = Cc;  N = Cc;  n0 = (idx % 32)*32; k0 = (idx / 32)*32; }
  else if (idx < 6144) { idx -= 4096; W = Wff1;  WT = Wff1T;  K = Cc;  N = FFf; n0 = (idx % 64)*32; k0 = (idx / 64)*32; }
  else                 { idx -= 6144; W = Wff2;  WT = Wff2T;  K = FFf; N = Cc;  n0 = (idx % 32)*32; k0 = (idx / 32)*32; }
  const int tx = threadIdx.x, ty = threadIdx.y;   // block (32,8)
  #pragma unroll
  for (int i = 0; i < 4; i++)
    tile[ty + 8*i][tx] = W[(size_t)(k0 + ty + 8*i) * N + n0 + tx];
  __syncthreads();
  #pragma unroll
  for (int i = 0; i < 4; i++)
    WT[(size_t)(n0 + ty + 8*i) * K + k0 + tx] = (f16)tile[tx][ty + 8*i];
}

// ---------------- LayerNorm: fp32 in -> f16 out ----------------
__global__ __launch_bounds__(256) void ln_kernel(const float* __restrict__ x,
                                                 const float* __restrict__ gam,
                                                 const float* __restrict__ bet,
                                                 f16* __restrict__ out) {
  const int row = blockIdx.x;
  const int tid = threadIdx.x;
  const float4 v = ((const float4*)(x + (size_t)row * Cc))[tid];
  float s  = v.x + v.y + v.z + v.w;
  float ss = v.x*v.x + v.y*v.y + v.z*v.z + v.w*v.w;
  #pragma unroll
  for (int o = 32; o >= 1; o >>= 1) { s += __shfl_xor(s, o); ss += __shfl_xor(ss, o); }
  __shared__ float ps[4], pss[4];
  if ((tid & 63) == 0) { ps[tid >> 6] = s; pss[tid >> 6] = ss; }
  __syncthreads();
  s  = ps[0] + ps[1] + ps[2] + ps[3];
  ss = pss[0] + pss[1] + pss[2] + pss[3];
  const float mu   = s * (1.0f / Cc);
  const float rstd = rsqrtf(ss * (1.0f / Cc) - mu * mu + 1e-5f);
  const float4 g4 = ((const float4*)gam)[tid];
  const float4 b4 = ((const float4*)bet)[tid];
  half4 o;
  o[0] = (f16)((v.x - mu) * rstd * g4.x + b4.x);
  o[1] = (f16)((v.y - mu) * rstd * g4.y + b4.y);
  o[2] = (f16)((v.z - mu) * rstd * g4.z + b4.z);
  o[3] = (f16)((v.w - mu) * rstd * g4.w + b4.w);
  ((half4*)(out + (size_t)row * Cc))[tid] = o;
}

// -------- shared epilogue helper (32x32 C layout: col=lane&31, row=(reg&3)+8*(reg>>2)+4*khalf) --------
template <int MODE>
__device__ __forceinline__ void gemm_epilogue_tile(
    const floatx16& a, int rowBase, int col, int khalf,
    const float* __restrict__ resid, const float* __restrict__ bias,
    float* __restrict__ outF, f16* __restrict__ outH,
    f16* __restrict__ outQ, f16* __restrict__ outK, f16* __restrict__ outV) {
  if (MODE == 0) {
    const int s = col >> 10;
    const int hh = (col >> 6) & 15;
    const int d = col & 63;
    #pragma unroll
    for (int g = 0; g < 4; g++) {
      const int row0 = rowBase + 4*khalf + 8*g;
      const int bI = row0 >> 11;
      const int t0 = row0 & 2047;
      if (s == 2) {
        const size_t addr = (((size_t)(bI*Hh + hh)) * Dd + d) * Tt +
                            (t0 & ~63) + ((t0 >> 2) & 3)*16 + ((t0 >> 4) & 3)*4;
        half4 o;
        #pragma unroll
        for (int r = 0; r < 4; r++) o[r] = (f16)a[g*4 + r];
        *(half4*)&outV[addr] = o;
      } else {
        f16* dst = (s == 0) ? outQ : outK;
        const float sc = (s == 0) ? 0.18033688f : 1.0f;  // (1/8)*log2(e) folded into q
        #pragma unroll
        for (int r = 0; r < 4; r++)
          dst[(((size_t)(bI*Hh + hh)) * Tt + t0 + r) * Dd + d] = (f16)(a[g*4 + r] * sc);
      }
    }
  } else {
    #pragma unroll
    for (int g = 0; g < 4; g++) {
      #pragma unroll
      for (int r = 0; r < 4; r++) {
        const int row = rowBase + 4*khalf + 8*g + r;
        const float vv = a[g*4 + r];
        if (MODE == 1) {
          const size_t ad = (size_t)row * Cc + col;
          outF[ad] = vv + resid[ad] + bias[col];
        } else if (MODE == 2) {
          const float t = vv + bias[col];
          const float gl = 0.5f * t * (1.0f + erff(t * 0.70710678118654752f));
          outH[(size_t)row * FFf + col] = (f16)gl;
        } else {
          const size_t ad = (size_t)row * Cc + col;
          outF[ad] = vv + bias[col] + resid[ad];
        }
      }
    }
  }
}

// ------------- GEMM 128x128: 32x32x16 MFMA, BK=64, swizzled staging, 4 blk/CU -------------
template <int MODE>
__global__ __launch_bounds__(256, 4) void gemm_kernel(
    const f16* __restrict__ A, const f16* __restrict__ Bt, const int Kdim,
    const float* __restrict__ resid, const float* __restrict__ bias,
    float* __restrict__ outF, f16* __restrict__ outH,
    f16* __restrict__ outQ, f16* __restrict__ outK, f16* __restrict__ outV) {
  __shared__ f16 As[128 * 64];
  __shared__ f16 Bs[128 * 64];
  const int tid = threadIdx.x;
  const int lane = tid & 63;
  const int w = tid >> 6;
  const int wr = w >> 1, wc = w & 1;
  const int bm = blockIdx.y, bn = blockIdx.x;

  floatx16 acc[2][2] = {};

  const int srow = lane >> 3;
  const int scol = ((lane & 7) ^ srow) * 8;
  const size_t aBase = (size_t)(bm*128 + w*32 + srow) * Kdim + scol;
  const size_t bBase = (size_t)(bn*128 + w*32 + srow) * Kdim + scol;

  const int m0 = wr*64 + (lane & 31);
  const int n0 = wc*64 + (lane & 31);
  const int khalf = lane >> 5;
  const int mx = (lane & 7);

  for (int ks = 0; ks < Kdim; ks += 64) {
    __syncthreads();
    #pragma unroll
    for (int c = 0; c < 4; c++) {
      g2l16(A  + aBase + (size_t)(c*8)*Kdim + ks, &As[(w*32 + c*8) * 64]);
      g2l16(Bt + bBase + (size_t)(c*8)*Kdim + ks, &Bs[(w*32 + c*8) * 64]);
    }
    __syncthreads();
    #pragma unroll
    for (int kk = 0; kk < 4; kk++) {
      const int kg = kk*2 + khalf;
      half8 aF[2], bF[2];
      aF[0] = *(const half8*)&As[(m0     ) * 64 + ((kg ^ mx) * 8)];
      aF[1] = *(const half8*)&As[(m0 + 32) * 64 + ((kg ^ mx) * 8)];
      bF[0] = *(const half8*)&Bs[(n0     ) * 64 + ((kg ^ mx) * 8)];
      bF[1] = *(const half8*)&Bs[(n0 + 32) * 64 + ((kg ^ mx) * 8)];
      acc[0][0] = MFMA32(aF[0], bF[0], acc[0][0]);
      acc[0][1] = MFMA32(aF[0], bF[1], acc[0][1]);
      acc[1][0] = MFMA32(aF[1], bF[0], acc[1][0]);
      acc[1][1] = MFMA32(aF[1], bF[1], acc[1][1]);
    }
  }

  #pragma unroll
  for (int mi = 0; mi < 2; mi++)
    #pragma unroll
    for (int ni = 0; ni < 2; ni++)
      gemm_epilogue_tile<MODE>(acc[mi][ni], blockIdx.y*128 + wr*64 + mi*32,
                               blockIdx.x*128 + wc*64 + ni*32 + (lane & 31), khalf,
                               resid, bias, outF, outH, outQ, outK, outV);
}

// ------- flash attention: 128-q tile, double-buffered 64-key staging, P in registers -------
// Prefetch tile kt+1 into buffer cur^1 right after the barrier, compute kt from buffer cur.
// The pre-barrier vmcnt drain then overlaps a full compute phase instead of stalling.
__global__ __launch_bounds__(256, 4) void attn_kernel(
    const f16* __restrict__ Q, const f16* __restrict__ Kg,
    const f16* __restrict__ Vtp, const int* __restrict__ perm,
    f16* __restrict__ Y) {
  __shared__ f16 Ks[2 * 4096];
  __shared__ f16 Vs[2 * 4096];
  __shared__ int permS[2 * 64];

  const int tid = threadIdx.x;
  const int lane = tid & 63;
  const int w = tid >> 6;
  const int low = lane & 15;
  const int quad = lane >> 4;
  const int bh = blockIdx.y;
  const int q0 = blockIdx.x * 128;
  const int b = bh >> 4, h = bh & 15;

  const int gd = ((lane & 7) ^ (lane >> 3)) * 8;
  const int krow = lane >> 3;

  const size_t kgBase0 = (size_t)bh * Tt * Dd;
  const size_t vgBase0 = (size_t)bh * Dd * Tt;

  auto stage = [&](int kt, int bufi) {
    const int kbase = kt * 64;
    g2l16(Kg  + kgBase0 + (size_t)(kbase + w*16 + 0 + krow) * Dd + gd, &Ks[bufi*4096 + (w*2 + 0) * 512]);
    g2l16(Kg  + kgBase0 + (size_t)(kbase + w*16 + 8 + krow) * Dd + gd, &Ks[bufi*4096 + (w*2 + 1) * 512]);
    g2l16(Vtp + vgBase0 + (size_t)(w*16 + 0 + krow) * Tt + kbase + gd, &Vs[bufi*4096 + (w*2 + 0) * 512]);
    g2l16(Vtp + vgBase0 + (size_t)(w*16 + 8 + krow) * Tt + kbase + gd, &Vs[bufi*4096 + (w*2 + 1) * 512]);
    if (tid < 64) permS[bufi*64 + tid] = perm[kbase + tid];
  };

  // Q fragments (B-operand of 16x16x32): qrow=low(+16qi), d=kc*32+quad*8+j
  half8 qF[2][2];
  {
    const size_t base = ((size_t)bh * Tt + q0 + w*32) * Dd;
    #pragma unroll
    for (int qi = 0; qi < 2; qi++)
      #pragma unroll
      for (int kc = 0; kc < 2; kc++)
        qF[qi][kc] = *(const half8*)(Q + base + (size_t)(qi*16 + low) * Dd +
                                     kc*32 + quad*8);
  }

  floatx4 O[4][2] = {};
  floatx4 Ol[2] = {};
  const half4 ones4 = {(f16)1.f, (f16)1.f, (f16)1.f, (f16)1.f};

  stage(0, 0);

  for (int kt = 0; kt < Tt / 64; kt++) {
    const int cur = kt & 1;
    __syncthreads();                     // staging(kt) drained; compute(kt-1) done
    if (kt + 1 < Tt / 64) stage(kt + 1, cur ^ 1);

    const f16* KsH = &Ks[cur * 4096];
    const f16* VsH = &Vs[cur * 4096];
    const int* pS  = &permS[cur * 64];

    // S^T = K Q^T : key = ki*16 + quad*4 + r, qrow = qi*16 + low
    floatx4 S[2][4] = {};
    #pragma unroll
    for (int kc = 0; kc < 2; kc++) {
      #pragma unroll
      for (int ki = 0; ki < 4; ki++) {
        const int key = ki*16 + low;
        const half8 kf = *(const half8*)&KsH[key * 64 + (((kc*4 + quad) ^ (lane & 7)) * 8)];
        S[0][ki] = MFMA16(kf, qF[0][kc], S[0][ki]);
        S[1][ki] = MFMA16(kf, qF[1][kc], S[1][ki]);
      }
    }

    int4 pk[4];
    #pragma unroll
    for (int ki = 0; ki < 4; ki++) pk[ki] = *(const int4*)&pS[ki*16 + quad*4];

    half4 pF[2][4];
    #pragma unroll
    for (int qi = 0; qi < 2; qi++) {
      const int qrow = q0 + w*32 + qi*16 + low;
      #pragma unroll
      for (int ki = 0; ki < 4; ki++) {
        const floatx4 sv = S[qi][ki];
        const float p0 = (pk[ki].x > qrow) ? 0.f : __builtin_amdgcn_exp2f(sv[0]);
        const float p1 = (pk[ki].y > qrow) ? 0.f : __builtin_amdgcn_exp2f(sv[1]);
        const float p2 = (pk[ki].z > qrow) ? 0.f : __builtin_amdgcn_exp2f(sv[2]);
        const float p3 = (pk[ki].w > qrow) ? 0.f : __builtin_amdgcn_exp2f(sv[3]);
        const half2 lo = __builtin_bit_cast(half2, __builtin_amdgcn_cvt_pkrtz(p0, p1));
        const half2 hi = __builtin_bit_cast(half2, __builtin_amdgcn_cvt_pkrtz(p2, p3));
        pF[qi][ki] = __builtin_shufflevector(lo, hi, 0, 1, 2, 3);
      }
    }

    #pragma unroll
    for (int ki2 = 0; ki2 < 2; ki2++) {
      Ol[0] = MFMA16K16(ones4, pF[0][2*ki2 + 0], Ol[0]);
      Ol[1] = MFMA16K16(ones4, pF[1][2*ki2 + 0], Ol[1]);
      Ol[0] = MFMA16K16(ones4, pF[0][2*ki2 + 1], Ol[0]);
      Ol[1] = MFMA16K16(ones4, pF[1][2*ki2 + 1], Ol[1]);
      #pragma unroll
      for (int ni = 0; ni < 4; ni++) {
        const int d = ni*16 + low;
        const half8 v8 = *(const half8*)&VsH[d * 64 + (((quad*2 + ki2) ^ (lane & 7)) * 8)];
        const half4 vfA = __builtin_shufflevector(v8, v8, 0, 1, 2, 3);
        const half4 vfB = __builtin_shufflevector(v8, v8, 4, 5, 6, 7);
        O[ni][0] = MFMA16K16(vfA, pF[0][2*ki2 + 0], O[ni][0]);
        O[ni][1] = MFMA16K16(vfA, pF[1][2*ki2 + 0], O[ni][1]);
        O[ni][0] = MFMA16K16(vfB, pF[0][2*ki2 + 1], O[ni][0]);
        O[ni][1] = MFMA16K16(vfB, pF[1][2*ki2 + 1], O[ni][1]);
      }
    }
  }

  // epilogue: O^T/l -> Y[b*T + trow][h*64 + d], d = ni*16 + quad*4 + r
  #pragma unroll
  for (int qi = 0; qi < 2; qi++) {
    const float linv = 1.0f / Ol[qi][0];
    const int trow = q0 + w*32 + qi*16 + low;
    #pragma unroll
    for (int ni = 0; ni < 4; ni++) {
      half4 o;
      #pragma unroll
      for (int r = 0; r < 4; r++) o[r] = (f16)(O[ni][qi][r] * linv);
      *(half4*)&Y[((size_t)(b * Tt + trow)) * Cc + h*64 + ni*16 + quad*4] = o;
    }
  }
}

extern "C" void kernel_launch(void* const* d_in, const int* in_sizes, int n_in,
                              void* d_out, int out_size, void* d_ws, size_t ws_size,
                              hipStream_t stream) {
  const float* x     = (const float*)d_in[0];
  const int*   perm  = (const int*)d_in[1];
  const float* Wqkv  = (const float*)d_in[2];
  const float* Wproj = (const float*)d_in[3];
  const float* bproj = (const float*)d_in[4];
  const float* ln1g  = (const float*)d_in[5];
  const float* ln1b  = (const float*)d_in[6];
  const float* ln2g  = (const float*)d_in[7];
  const float* ln2b  = (const float*)d_in[8];
  const float* Wff1  = (const float*)d_in[9];
  const float* bff1  = (const float*)d_in[10];
  const float* Wff2  = (const float*)d_in[11];
  const float* bff2  = (const float*)d_in[12];
  float* out = (float*)d_out;

  char* ws = (char*)d_ws;
  size_t off = 0;
  auto alloc = [&](size_t bytes) -> void* {
    void* p = ws + off;
    off += (bytes + 255) & ~(size_t)255;
    return p;
  };
  f16*   h1     = (f16*)alloc((size_t)Mrows * Cc * 2);
  f16*   qb     = (f16*)alloc((size_t)Mrows * Cc * 2);
  f16*   kb     = (f16*)alloc((size_t)Mrows * Cc * 2);
  f16*   vtp    = (f16*)alloc((size_t)Mrows * Cc * 2);
  f16*   yb     = (f16*)alloc((size_t)Mrows * Cc * 2);
  float* xa     = (float*)alloc((size_t)Mrows * Cc * 4);
  f16*   h2     = (f16*)alloc((size_t)Mrows * Cc * 2);
  f16*   gb     = (f16*)alloc((size_t)Mrows * FFf * 2);
  f16*   WqkvT  = (f16*)alloc((size_t)3 * Cc * Cc * 2);
  f16*   WprojT = (f16*)alloc((size_t)Cc * Cc * 2);
  f16*   Wff1T  = (f16*)alloc((size_t)FFf * Cc * 2);
  f16*   Wff2T  = (f16*)alloc((size_t)Cc * FFf * 2);

  wt_all_kernel<<<8192, dim3(32, 8), 0, stream>>>(Wqkv, Wproj, Wff1, Wff2,
                                                  WqkvT, WprojT, Wff1T, Wff2T);

  ln_kernel<<<Mrows, 256, 0, stream>>>(x, ln1g, ln1b, h1);

  gemm_kernel<0><<<dim3(3*Cc/128, Mrows/128), 256, 0, stream>>>(
      h1, WqkvT, Cc, nullptr, nullptr, nullptr, nullptr, qb, kb, vtp);

  attn_kernel<<<dim3(Tt/128, Bb*Hh), 256, 0, stream>>>(qb, kb, vtp, perm, yb);

  gemm_kernel<1><<<dim3(Cc/128, Mrows/128), 256, 0, stream>>>(
      yb, WprojT, Cc, x, bproj, xa, nullptr, nullptr, nullptr, nullptr);

  ln_kernel<<<Mrows, 256, 0, stream>>>(xa, ln2g, ln2b, h2);

  gemm_kernel<2><<<dim3(FFf/128, Mrows/128), 256, 0, stream>>>(
      h2, Wff1T, Cc, nullptr, bff1, nullptr, gb, nullptr, nullptr, nullptr);

  gemm_kernel<3><<<dim3(Cc/128, Mrows/128), 256, 0, stream>>>(
      gb, Wff2T, FFf, xa, bff2, out, nullptr, nullptr, nullptr, nullptr);
}

// Round 13
// 435.254 us; speedup vs baseline: 1.0359x; 1.0302x over previous
//
#include <hip/hip_runtime.h>
#include <math.h>

#define Bb 4
#define Tt 2048
#define Cc 1024
#define Hh 16
#define Dd 64
#define FFf 2048
#define Mrows (Bb*Tt)   // 8192

typedef _Float16 f16;
typedef _Float16 half8 __attribute__((ext_vector_type(8)));
typedef _Float16 half4 __attribute__((ext_vector_type(4)));
typedef _Float16 half2 __attribute__((ext_vector_type(2)));
typedef float floatx4 __attribute__((ext_vector_type(4)));
typedef float floatx16 __attribute__((ext_vector_type(16)));

#define MFMA16(a,b,c)    __builtin_amdgcn_mfma_f32_16x16x32_f16(a,b,c,0,0,0)
#define MFMA16K16(a,b,c) __builtin_amdgcn_mfma_f32_16x16x16f16(a,b,c,0,0,0)
#define MFMA32(a,b,c)    __builtin_amdgcn_mfma_f32_32x32x16_f16(a,b,c,0,0,0)

// async global->LDS, 16B per lane; LDS dest = wave-uniform base + lane*16
__device__ __forceinline__ void g2l16(const void* g, void* l) {
  __builtin_amdgcn_global_load_lds((__attribute__((address_space(1))) void*)(g),
                                   (__attribute__((address_space(3))) void*)(l),
                                   16, 0, 0);
}

// ---- fused: weight transpose (blocks 0..8191) + LayerNorm1 (blocks 8192..16383) ----
__global__ __launch_bounds__(256) void wt_ln_kernel(
    const float* __restrict__ Wqkv, const float* __restrict__ Wproj,
    const float* __restrict__ Wff1, const float* __restrict__ Wff2,
    f16* __restrict__ WqkvT, f16* __restrict__ WprojT,
    f16* __restrict__ Wff1T, f16* __restrict__ Wff2T,
    const float* __restrict__ x, const float* __restrict__ gam,
    const float* __restrict__ bet, f16* __restrict__ lnout) {
  const int tid = threadIdx.x;
  if (blockIdx.x < 8192) {
    __shared__ float tile[32][33];
    int idx = blockIdx.x;
    const float* W; f16* WT; int K, N, n0, k0;
    if (idx < 3072)      { W = Wqkv;  WT = WqkvT;  K = Cc;  N = 3*Cc; n0 = (idx % 96)*32; k0 = (idx / 96)*32; }
    else if (idx < 4096) { idx -= 3072; W = Wproj; WT = WprojT; K = Cc;  N = Cc;  n0 = (idx % 32)*32; k0 = (idx / 32)*32; }
    else if (idx < 6144) { idx -= 4096; W = Wff1;  WT = Wff1T;  K = Cc;  N = FFf; n0 = (idx % 64)*32; k0 = (idx / 64)*32; }
    else                 { idx -= 6144; W = Wff2;  WT = Wff2T;  K = FFf; N = Cc;  n0 = (idx % 32)*32; k0 = (idx / 32)*32; }
    const int tx = tid & 31, ty = tid >> 5;
    #pragma unroll
    for (int i = 0; i < 4; i++)
      tile[ty + 8*i][tx] = W[(size_t)(k0 + ty + 8*i) * N + n0 + tx];
    __syncthreads();
    #pragma unroll
    for (int i = 0; i < 4; i++)
      WT[(size_t)(n0 + ty + 8*i) * K + k0 + tx] = (f16)tile[tx][ty + 8*i];
  } else {
    const int row = blockIdx.x - 8192;
    const float4 v = ((const float4*)(x + (size_t)row * Cc))[tid];
    float s  = v.x + v.y + v.z + v.w;
    float ss = v.x*v.x + v.y*v.y + v.z*v.z + v.w*v.w;
    #pragma unroll
    for (int o = 32; o >= 1; o >>= 1) { s += __shfl_xor(s, o); ss += __shfl_xor(ss, o); }
    __shared__ float ps[4], pss[4];
    if ((tid & 63) == 0) { ps[tid >> 6] = s; pss[tid >> 6] = ss; }
    __syncthreads();
    s  = ps[0] + ps[1] + ps[2] + ps[3];
    ss = pss[0] + pss[1] + pss[2] + pss[3];
    const float mu   = s * (1.0f / Cc);
    const float rstd = rsqrtf(ss * (1.0f / Cc) - mu * mu + 1e-5f);
    const float4 g4 = ((const float4*)gam)[tid];
    const float4 b4 = ((const float4*)bet)[tid];
    half4 o;
    o[0] = (f16)((v.x - mu) * rstd * g4.x + b4.x);
    o[1] = (f16)((v.y - mu) * rstd * g4.y + b4.y);
    o[2] = (f16)((v.z - mu) * rstd * g4.z + b4.z);
    o[3] = (f16)((v.w - mu) * rstd * g4.w + b4.w);
    ((half4*)(lnout + (size_t)row * Cc))[tid] = o;
  }
}

// ---------------- LayerNorm: fp32 in -> f16 out ----------------
__global__ __launch_bounds__(256) void ln_kernel(const float* __restrict__ x,
                                                 const float* __restrict__ gam,
                                                 const float* __restrict__ bet,
                                                 f16* __restrict__ out) {
  const int row = blockIdx.x;
  const int tid = threadIdx.x;
  const float4 v = ((const float4*)(x + (size_t)row * Cc))[tid];
  float s  = v.x + v.y + v.z + v.w;
  float ss = v.x*v.x + v.y*v.y + v.z*v.z + v.w*v.w;
  #pragma unroll
  for (int o = 32; o >= 1; o >>= 1) { s += __shfl_xor(s, o); ss += __shfl_xor(ss, o); }
  __shared__ float ps[4], pss[4];
  if ((tid & 63) == 0) { ps[tid >> 6] = s; pss[tid >> 6] = ss; }
  __syncthreads();
  s  = ps[0] + ps[1] + ps[2] + ps[3];
  ss = pss[0] + pss[1] + pss[2] + pss[3];
  const float mu   = s * (1.0f / Cc);
  const float rstd = rsqrtf(ss * (1.0f / Cc) - mu * mu + 1e-5f);
  const float4 g4 = ((const float4*)gam)[tid];
  const float4 b4 = ((const float4*)bet)[tid];
  half4 o;
  o[0] = (f16)((v.x - mu) * rstd * g4.x + b4.x);
  o[1] = (f16)((v.y - mu) * rstd * g4.y + b4.y);
  o[2] = (f16)((v.z - mu) * rstd * g4.z + b4.z);
  o[3] = (f16)((v.w - mu) * rstd * g4.w + b4.w);
  ((half4*)(out + (size_t)row * Cc))[tid] = o;
}

// -------- shared epilogue helper (32x32 C layout: col=lane&31, row=(reg&3)+8*(reg>>2)+4*khalf) --------
template <int MODE>
__device__ __forceinline__ void gemm_epilogue_tile(
    const floatx16& a, int rowBase, int col, int khalf,
    const float* __restrict__ resid, const float* __restrict__ bias,
    float* __restrict__ outF, f16* __restrict__ outH,
    f16* __restrict__ outQ, f16* __restrict__ outK, f16* __restrict__ outV) {
  if (MODE == 0) {
    const int s = col >> 10;
    const int hh = (col >> 6) & 15;
    const int d = col & 63;
    #pragma unroll
    for (int g = 0; g < 4; g++) {
      const int row0 = rowBase + 4*khalf + 8*g;
      const int bI = row0 >> 11;
      const int t0 = row0 & 2047;
      if (s == 2) {
        const size_t addr = (((size_t)(bI*Hh + hh)) * Dd + d) * Tt +
                            (t0 & ~63) + ((t0 >> 2) & 3)*16 + ((t0 >> 4) & 3)*4;
        half4 o;
        #pragma unroll
        for (int r = 0; r < 4; r++) o[r] = (f16)a[g*4 + r];
        *(half4*)&outV[addr] = o;
      } else {
        f16* dst = (s == 0) ? outQ : outK;
        const float sc = (s == 0) ? 0.18033688f : 1.0f;  // (1/8)*log2(e) folded into q
        #pragma unroll
        for (int r = 0; r < 4; r++)
          dst[(((size_t)(bI*Hh + hh)) * Tt + t0 + r) * Dd + d] = (f16)(a[g*4 + r] * sc);
      }
    }
  } else {
    #pragma unroll
    for (int g = 0; g < 4; g++) {
      #pragma unroll
      for (int r = 0; r < 4; r++) {
        const int row = rowBase + 4*khalf + 8*g + r;
        const float vv = a[g*4 + r];
        if (MODE == 1) {
          const size_t ad = (size_t)row * Cc + col;
          outF[ad] = vv + resid[ad] + bias[col];
        } else if (MODE == 2) {
          const float t = vv + bias[col];
          const float gl = 0.5f * t * (1.0f + erff(t * 0.70710678118654752f));
          outH[(size_t)row * FFf + col] = (f16)gl;
        } else {
          const size_t ad = (size_t)row * Cc + col;
          outF[ad] = vv + bias[col] + resid[ad];
        }
      }
    }
  }
}

// ------------- GEMM 128x128: 32x32x16 MFMA, BK=64, swizzled staging, 4 blk/CU -------------
// XCD-aware block remap: consecutive dispatch ids round-robin over 8 XCDs; remap so each
// XCD processes one bn (B-slab, ~256 KB) at a time -> B stays resident in that XCD's L2.
template <int MODE>
__global__ __launch_bounds__(256, 4) void gemm_kernel(
    const f16* __restrict__ A, const f16* __restrict__ Bt, const int Kdim,
    const float* __restrict__ resid, const float* __restrict__ bias,
    float* __restrict__ outF, f16* __restrict__ outH,
    f16* __restrict__ outQ, f16* __restrict__ outK, f16* __restrict__ outV) {
  __shared__ f16 As[128 * 64];
  __shared__ f16 Bs[128 * 64];
  const int tid = threadIdx.x;
  const int lane = tid & 63;
  const int w = tid >> 6;
  const int wr = w >> 1, wc = w & 1;

  const int Mb = gridDim.y;
  const int fid = blockIdx.y * gridDim.x + blockIdx.x;  // dispatch-linear id
  const int xcd = fid & 7;
  const int slot = fid >> 3;
  const int bn = xcd + 8 * (slot / Mb);
  const int bm = slot % Mb;

  floatx16 acc[2][2] = {};

  const int srow = lane >> 3;
  const int scol = ((lane & 7) ^ srow) * 8;
  const size_t aBase = (size_t)(bm*128 + w*32 + srow) * Kdim + scol;
  const size_t bBase = (size_t)(bn*128 + w*32 + srow) * Kdim + scol;

  const int m0 = wr*64 + (lane & 31);
  const int n0 = wc*64 + (lane & 31);
  const int khalf = lane >> 5;
  const int mx = (lane & 7);

  for (int ks = 0; ks < Kdim; ks += 64) {
    __syncthreads();
    #pragma unroll
    for (int c = 0; c < 4; c++) {
      g2l16(A  + aBase + (size_t)(c*8)*Kdim + ks, &As[(w*32 + c*8) * 64]);
      g2l16(Bt + bBase + (size_t)(c*8)*Kdim + ks, &Bs[(w*32 + c*8) * 64]);
    }
    __syncthreads();
    #pragma unroll
    for (int kk = 0; kk < 4; kk++) {
      const int kg = kk*2 + khalf;
      half8 aF[2], bF[2];
      aF[0] = *(const half8*)&As[(m0     ) * 64 + ((kg ^ mx) * 8)];
      aF[1] = *(const half8*)&As[(m0 + 32) * 64 + ((kg ^ mx) * 8)];
      bF[0] = *(const half8*)&Bs[(n0     ) * 64 + ((kg ^ mx) * 8)];
      bF[1] = *(const half8*)&Bs[(n0 + 32) * 64 + ((kg ^ mx) * 8)];
      acc[0][0] = MFMA32(aF[0], bF[0], acc[0][0]);
      acc[0][1] = MFMA32(aF[0], bF[1], acc[0][1]);
      acc[1][0] = MFMA32(aF[1], bF[0], acc[1][0]);
      acc[1][1] = MFMA32(aF[1], bF[1], acc[1][1]);
    }
  }

  #pragma unroll
  for (int mi = 0; mi < 2; mi++)
    #pragma unroll
    for (int ni = 0; ni < 2; ni++)
      gemm_epilogue_tile<MODE>(acc[mi][ni], bm*128 + wr*64 + mi*32,
                               bn*128 + wc*64 + ni*32 + (lane & 31), khalf,
                               resid, bias, outF, outH, outQ, outK, outV);
}

// ---------------- flash attention: 128-q tile, 64-key staging, P in registers ----------------
// (R9 structure — best measured 103.4 µs; dbuf variant regressed, reverted.)
__global__ __launch_bounds__(256, 4) void attn_kernel(
    const f16* __restrict__ Q, const f16* __restrict__ Kg,
    const f16* __restrict__ Vtp, const int* __restrict__ perm,
    f16* __restrict__ Y) {
  __shared__ f16 Ks[64 * 64];
  __shared__ f16 Vs[64 * 64];
  __shared__ int permS[64];

  const int tid = threadIdx.x;
  const int lane = tid & 63;
  const int w = tid >> 6;
  const int low = lane & 15;
  const int quad = lane >> 4;
  const int bh = blockIdx.y;
  const int q0 = blockIdx.x * 128;
  const int b = bh >> 4, h = bh & 15;

  half8 qF[2][2];
  {
    const size_t base = ((size_t)bh * Tt + q0 + w*32) * Dd;
    #pragma unroll
    for (int qi = 0; qi < 2; qi++)
      #pragma unroll
      for (int kc = 0; kc < 2; kc++)
        qF[qi][kc] = *(const half8*)(Q + base + (size_t)(qi*16 + low) * Dd +
                                     kc*32 + quad*8);
  }

  floatx4 O[4][2] = {};
  floatx4 Ol[2] = {};
  const half4 ones4 = {(f16)1.f, (f16)1.f, (f16)1.f, (f16)1.f};

  const int gd = ((lane & 7) ^ (lane >> 3)) * 8;
  const int krow = lane >> 3;

  for (int kt = 0; kt < Tt / 64; kt++) {
    const int kbase = kt * 64;
    __syncthreads();
    {
      const size_t kgBase = ((size_t)bh * Tt + kbase) * Dd;
      const size_t vgBase = ((size_t)bh * Dd) * Tt + kbase;
      g2l16(Kg  + kgBase + (size_t)(w*16 + 0 + krow) * Dd + gd, &Ks[(w*2 + 0) * 512]);
      g2l16(Kg  + kgBase + (size_t)(w*16 + 8 + krow) * Dd + gd, &Ks[(w*2 + 1) * 512]);
      g2l16(Vtp + vgBase + (size_t)(w*16 + 0 + krow) * Tt + gd, &Vs[(w*2 + 0) * 512]);
      g2l16(Vtp + vgBase + (size_t)(w*16 + 8 + krow) * Tt + gd, &Vs[(w*2 + 1) * 512]);
      if (tid < 64) permS[tid] = perm[kbase + tid];
    }
    __syncthreads();

    floatx4 S[2][4] = {};
    #pragma unroll
    for (int kc = 0; kc < 2; kc++) {
      #pragma unroll
      for (int ki = 0; ki < 4; ki++) {
        const int key = ki*16 + low;
        const half8 kf = *(const half8*)&Ks[key * 64 + (((kc*4 + quad) ^ (lane & 7)) * 8)];
        S[0][ki] = MFMA16(kf, qF[0][kc], S[0][ki]);
        S[1][ki] = MFMA16(kf, qF[1][kc], S[1][ki]);
      }
    }

    int4 pk[4];
    #pragma unroll
    for (int ki = 0; ki < 4; ki++) pk[ki] = *(const int4*)&permS[ki*16 + quad*4];

    half4 pF[2][4];
    #pragma unroll
    for (int qi = 0; qi < 2; qi++) {
      const int qrow = q0 + w*32 + qi*16 + low;
      #pragma unroll
      for (int ki = 0; ki < 4; ki++) {
        const floatx4 sv = S[qi][ki];
        const float p0 = (pk[ki].x > qrow) ? 0.f : __builtin_amdgcn_exp2f(sv[0]);
        const float p1 = (pk[ki].y > qrow) ? 0.f : __builtin_amdgcn_exp2f(sv[1]);
        const float p2 = (pk[ki].z > qrow) ? 0.f : __builtin_amdgcn_exp2f(sv[2]);
        const float p3 = (pk[ki].w > qrow) ? 0.f : __builtin_amdgcn_exp2f(sv[3]);
        const half2 lo = __builtin_bit_cast(half2, __builtin_amdgcn_cvt_pkrtz(p0, p1));
        const half2 hi = __builtin_bit_cast(half2, __builtin_amdgcn_cvt_pkrtz(p2, p3));
        pF[qi][ki] = __builtin_shufflevector(lo, hi, 0, 1, 2, 3);
      }
    }

    #pragma unroll
    for (int ki2 = 0; ki2 < 2; ki2++) {
      Ol[0] = MFMA16K16(ones4, pF[0][2*ki2 + 0], Ol[0]);
      Ol[1] = MFMA16K16(ones4, pF[1][2*ki2 + 0], Ol[1]);
      Ol[0] = MFMA16K16(ones4, pF[0][2*ki2 + 1], Ol[0]);
      Ol[1] = MFMA16K16(ones4, pF[1][2*ki2 + 1], Ol[1]);
      #pragma unroll
      for (int ni = 0; ni < 4; ni++) {
        const int d = ni*16 + low;
        const half8 v8 = *(const half8*)&Vs[d * 64 + (((quad*2 + ki2) ^ (lane & 7)) * 8)];
        const half4 vfA = __builtin_shufflevector(v8, v8, 0, 1, 2, 3);
        const half4 vfB = __builtin_shufflevector(v8, v8, 4, 5, 6, 7);
        O[ni][0] = MFMA16K16(vfA, pF[0][2*ki2 + 0], O[ni][0]);
        O[ni][1] = MFMA16K16(vfA, pF[1][2*ki2 + 0], O[ni][1]);
        O[ni][0] = MFMA16K16(vfB, pF[0][2*ki2 + 1], O[ni][0]);
        O[ni][1] = MFMA16K16(vfB, pF[1][2*ki2 + 1], O[ni][1]);
      }
    }
  }

  #pragma unroll
  for (int qi = 0; qi < 2; qi++) {
    const float linv = 1.0f / Ol[qi][0];
    const int trow = q0 + w*32 + qi*16 + low;
    #pragma unroll
    for (int ni = 0; ni < 4; ni++) {
      half4 o;
      #pragma unroll
      for (int r = 0; r < 4; r++) o[r] = (f16)(O[ni][qi][r] * linv);
      *(half4*)&Y[((size_t)(b * Tt + trow)) * Cc + h*64 + ni*16 + quad*4] = o;
    }
  }
}

extern "C" void kernel_launch(void* const* d_in, const int* in_sizes, int n_in,
                              void* d_out, int out_size, void* d_ws, size_t ws_size,
                              hipStream_t stream) {
  const float* x     = (const float*)d_in[0];
  const int*   perm  = (const int*)d_in[1];
  const float* Wqkv  = (const float*)d_in[2];
  const float* Wproj = (const float*)d_in[3];
  const float* bproj = (const float*)d_in[4];
  const float* ln1g  = (const float*)d_in[5];
  const float* ln1b  = (const float*)d_in[6];
  const float* ln2g  = (const float*)d_in[7];
  const float* ln2b  = (const float*)d_in[8];
  const float* Wff1  = (const float*)d_in[9];
  const float* bff1  = (const float*)d_in[10];
  const float* Wff2  = (const float*)d_in[11];
  const float* bff2  = (const float*)d_in[12];
  float* out = (float*)d_out;

  char* ws = (char*)d_ws;
  size_t off = 0;
  auto alloc = [&](size_t bytes) -> void* {
    void* p = ws + off;
    off += (bytes + 255) & ~(size_t)255;
    return p;
  };
  f16*   h1     = (f16*)alloc((size_t)Mrows * Cc * 2);
  f16*   qb     = (f16*)alloc((size_t)Mrows * Cc * 2);
  f16*   kb     = (f16*)alloc((size_t)Mrows * Cc * 2);
  f16*   vtp    = (f16*)alloc((size_t)Mrows * Cc * 2);
  f16*   yb     = (f16*)alloc((size_t)Mrows * Cc * 2);
  float* xa     = (float*)alloc((size_t)Mrows * Cc * 4);
  f16*   h2     = (f16*)alloc((size_t)Mrows * Cc * 2);
  f16*   gb     = (f16*)alloc((size_t)Mrows * FFf * 2);
  f16*   WqkvT  = (f16*)alloc((size_t)3 * Cc * Cc * 2);
  f16*   WprojT = (f16*)alloc((size_t)Cc * Cc * 2);
  f16*   Wff1T  = (f16*)alloc((size_t)FFf * Cc * 2);
  f16*   Wff2T  = (f16*)alloc((size_t)Cc * FFf * 2);

  wt_ln_kernel<<<16384, 256, 0, stream>>>(Wqkv, Wproj, Wff1, Wff2,
                                          WqkvT, WprojT, Wff1T, Wff2T,
                                          x, ln1g, ln1b, h1);

  gemm_kernel<0><<<dim3(3*Cc/128, Mrows/128), 256, 0, stream>>>(
      h1, WqkvT, Cc, nullptr, nullptr, nullptr, nullptr, qb, kb, vtp);

  attn_kernel<<<dim3(Tt/128, Bb*Hh), 256, 0, stream>>>(qb, kb, vtp, perm, yb);

  gemm_kernel<1><<<dim3(Cc/128, Mrows/128), 256, 0, stream>>>(
      yb, WprojT, Cc, x, bproj, xa, nullptr, nullptr, nullptr, nullptr);

  ln_kernel<<<Mrows, 256, 0, stream>>>(xa, ln2g, ln2b, h2);

  gemm_kernel<2><<<dim3(FFf/128, Mrows/128), 256, 0, stream>>>(
      h2, Wff1T, Cc, nullptr, bff1, nullptr, gb, nullptr, nullptr, nullptr);

  gemm_kernel<3><<<dim3(Cc/128, Mrows/128), 256, 0, stream>>>(
      gb, Wff2T, FFf, xa, bff2, out, nullptr, nullptr, nullptr, nullptr);
}